// Round 1
// baseline (584.626 us; speedup 1.0000x reference)
//
#include <hip/hip_runtime.h>
#include <hip/hip_bf16.h>
#include <math.h>

// Problem constants (from reference setup_inputs)
#define P_ 4
#define B_ 128
#define D_ 512
#define N_ 32768
#define K_ 10
#define TNB 128          // n-tile per block in neg_mfma_kernel
#define NT2 (N_ / TNB)   // 256 tiles per p
#define BK2 32           // k-chunk (1 MFMA K-step)
#define NCH (D_ / BK2)   // 16 chunks
#define KP2 40           // padded LDS row stride in shorts (32 + 8)

typedef __attribute__((ext_vector_type(8))) short bf16x8;   // 8 bf16 (4 VGPRs)
typedef __attribute__((ext_vector_type(4))) float f32x4;    // MFMA acc

// Workgroup barrier that does NOT drain vmcnt: own LDS ops must be complete
// (lgkmcnt(0)) for cross-thread visibility, but register-destined global
// loads may stay in flight across the barrier (counted-vmcnt discipline —
// the compiler inserts the exact vmcnt(N) at each use site).
#define LDS_BARRIER() asm volatile("s_waitcnt lgkmcnt(0)\n\ts_barrier" ::: "memory")

static __device__ __forceinline__ float block_sum_128(float v, float* sh) {
    const int t = threadIdx.x;
    sh[t] = v; __syncthreads();
    #pragma unroll
    for (int s = 64; s > 0; s >>= 1) { if (t < s) sh[t] += sh[t + s]; __syncthreads(); }
    float r = sh[0]; __syncthreads();
    return r;
}

static __device__ __forceinline__ uint2 pack_bf16x4(float4 v) {
    union { __hip_bfloat162 h; unsigned u; } lo, hi;
    lo.h = __float22bfloat162_rn(make_float2(v.x, v.y));   // RNE
    hi.h = __float22bfloat162_rn(make_float2(v.z, v.w));
    uint2 r; r.x = lo.u; r.y = hi.u;
    return r;
}

// ---------- sim: fused normalize + similarity + valid; also zeroes Ssum ----------
// img_sim[p,b,c] = 2 * (f_b . f_c) * inv|f_b| * inv|f_c|  (dot-then-scale)
__global__ __launch_bounds__(128) void sim_kernel(
    const float* __restrict__ feature,
    const float* __restrict__ text_feature,
    float* __restrict__ img_sim,
    float* __restrict__ txt_sim,
    float* __restrict__ validf,
    float* __restrict__ Ssum) {
    const int p = blockIdx.x;
    const int b0 = blockIdx.y * 2;        // 2 rows per block
    const int c = threadIdx.x;            // 128 threads, one column each
    if (blockIdx.y == 0) Ssum[p * B_ + c] = 0.0f;   // zero accumulator for neg_mfma
    __shared__ float ai[2][D_];
    __shared__ float at[2][D_];
    __shared__ float cinv_i[128];
    __shared__ float cinv_t[128];
    __shared__ int flags[2];
    #pragma unroll
    for (int i = 0; i < 8; ++i) {
        int idx = c + i * 128;            // 0..1023
        int row = idx >> 9, d = idx & 511;
        ai[row][d] = feature[(size_t)(p * B_ + b0 + row) * D_ + d];
        at[row][d] = text_feature[((size_t)(b0 + row) * P_ + p) * D_ + d];
    }
    if (c < 2) flags[c] = 0;
    __syncthreads();
    float di[2] = {0, 0};
    float dt[2] = {0, 0};
    float ssi = 0.0f, sst = 0.0f;         // column sumsq (raw)
    const float* fc = feature + (size_t)(p * B_ + c) * D_;
    const float* tc = text_feature + ((size_t)c * P_ + p) * D_;
    for (int d = 0; d < D_; d += 4) {
        float4 vi = *(const float4*)(fc + d);
        float4 vt = *(const float4*)(tc + d);
        ssi += vi.x * vi.x + vi.y * vi.y + vi.z * vi.z + vi.w * vi.w;
        sst += vt.x * vt.x + vt.y * vt.y + vt.z * vt.z + vt.w * vt.w;
        #pragma unroll
        for (int i = 0; i < 2; ++i) {
            float4 a4 = *(const float4*)&ai[i][d];
            float4 t4 = *(const float4*)&at[i][d];
            di[i] += a4.x * vi.x + a4.y * vi.y + a4.z * vi.z + a4.w * vi.w;
            dt[i] += t4.x * vt.x + t4.y * vt.y + t4.z * vt.z + t4.w * vt.w;
        }
    }
    cinv_i[c] = 1.0f / fmaxf(sqrtf(ssi), 1e-12f);
    cinv_t[c] = 1.0f / fmaxf(sqrtf(sst), 1e-12f);
    __syncthreads();
    #pragma unroll
    for (int i = 0; i < 2; ++i) {
        float is = 2.0f * di[i] * cinv_i[b0 + i] * cinv_i[c];   // / TEMP (0.5)
        float ts = 2.0f * dt[i] * cinv_t[b0 + i] * cinv_t[c];
        img_sim[(size_t)(p * B_ + b0 + i) * B_ + c] = is;
        txt_sim[(size_t)(p * B_ + b0 + i) * B_ + c] = ts;
        if (is > 0.7f && ts > 0.7f) flags[i] = 1;   // benign write race
    }
    __syncthreads();
    if (c < 2) validf[p * B_ + b0 + c] = (float)flags[c];
}

// ---------- per-row masked log-softmax + symmetric KL (one wave per row) ----------
__global__ __launch_bounds__(256) void kl_kernel(
    const float* __restrict__ img_sim,
    const float* __restrict__ txt_sim,
    const float* __restrict__ validf,
    float* __restrict__ klrow) {
    const int l = threadIdx.x & 63;
    const int wv = threadIdx.x >> 6;
    const int p = blockIdx.x;
    const int r = blockIdx.y * 4 + wv;
    const size_t base = (size_t)(p * B_ + r) * B_;
    const bool v0 = validf[p * B_ + l] > 0.5f;
    const bool v1 = validf[p * B_ + 64 + l] > 0.5f;
    const float il0 = v0 ? img_sim[base + l] : -1e30f;
    const float il1 = v1 ? img_sim[base + 64 + l] : -1e30f;
    const float tl0 = v0 ? txt_sim[base + l] : -1e30f;
    const float tl1 = v1 ? txt_sim[base + 64 + l] : -1e30f;
    float mi = fmaxf(il0, il1), mt = fmaxf(tl0, tl1);
    #pragma unroll
    for (int off = 32; off > 0; off >>= 1) {
        mi = fmaxf(mi, __shfl_xor(mi, off));
        mt = fmaxf(mt, __shfl_xor(mt, off));
    }
    float si = expf(il0 - mi) + expf(il1 - mi);
    float st = expf(tl0 - mt) + expf(tl1 - mt);
    #pragma unroll
    for (int off = 32; off > 0; off >>= 1) {
        si += __shfl_xor(si, off);
        st += __shfl_xor(st, off);
    }
    const float lsei = mi + logf(si);
    const float lset = mt + logf(st);
    float term = 0.0f;
    if (v0) {
        float lpi = il0 - lsei, lpt = tl0 - lset;
        term += expf(lpt) * (lpt - lpi) + expf(lpi) * (lpi - lpt);
    }
    if (v1) {
        float lpi = il1 - lsei, lpt = tl1 - lset;
        term += expf(lpt) * (lpt - lpi) + expf(lpi) * (lpi - lpt);
    }
    #pragma unroll
    for (int off = 32; off > 0; off >>= 1) term += __shfl_xor(term, off);
    if (l == 0) klrow[p * B_ + r] = (validf[p * B_ + r] > 0.5f) ? term : 0.0f;
}

// ---------- x[p,b] = log sum_k exp(-SCALE * pos_dist); fn2 computed inline ----------
__global__ void posx_kernel(const float* __restrict__ feature,
                            const float* __restrict__ centers,
                            const int* __restrict__ cross,
                            float* __restrict__ xarr) {
    const int pb = blockIdx.x;
    const int p = pb >> 7, b = pb & 127;
    const int l = threadIdx.x;            // 64 (one wave)
    const float* f = feature + (size_t)pb * D_;
    float4 f0 = *(const float4*)(f + l * 4);
    float4 f1 = *(const float4*)(f + 256 + l * 4);
    float fs = f0.x * f0.x + f0.y * f0.y + f0.z * f0.z + f0.w * f0.w
             + f1.x * f1.x + f1.y * f1.y + f1.z * f1.z + f1.w * f1.w;
    #pragma unroll
    for (int off = 32; off > 0; off >>= 1) fs += __shfl_down(fs, off);
    // fs = ||f||^2 valid on lane 0
    float ex = 0.0f;
    #pragma unroll
    for (int k = 0; k < K_; ++k) {
        int idx = cross[b * K_ + k];
        const float* cp = centers + ((size_t)p * N_ + idx) * D_;
        float4 c0 = *(const float4*)(cp + l * 4);
        float4 c1 = *(const float4*)(cp + 256 + l * 4);
        float dot = f0.x * c0.x + f0.y * c0.y + f0.z * c0.z + f0.w * c0.w
                  + f1.x * c1.x + f1.y * c1.y + f1.z * c1.z + f1.w * c1.w;
        float pn2 = c0.x * c0.x + c0.y * c0.y + c0.z * c0.z + c0.w * c0.w
                  + c1.x * c1.x + c1.y * c1.y + c1.z * c1.z + c1.w * c1.w;
        #pragma unroll
        for (int off = 32; off > 0; off >>= 1) {
            dot += __shfl_down(dot, off);
            pn2 += __shfl_down(pn2, off);
        }
        if (l == 0) {
            float d2 = fs + pn2 - 2.0f * dot;
            ex += expf(-10.0f * sqrtf(fmaxf(d2, 1e-12f)));
        }
    }
    if (l == 0) xarr[pb] = logf(ex);
}

// ---------- main kernel: bf16 MFMA GEMM + fused sqrt/exp/mask epilogue ----------
// v2: (a) non-draining barriers (lgkmcnt(0)+s_barrier, counted vmcnt preserved
// across barriers), (b) 2-deep register prefetch (issue chunk c+2 at top of
// chunk c), (c) column mask built in-LDS from cross/position, (d) fn2 computed
// from the staged A tile, (e) partial sums accumulated into Ssum via atomics.
__global__ __launch_bounds__(256, 2) void neg_mfma_kernel(
    const float* __restrict__ feature,
    const float* __restrict__ centers,
    const int* __restrict__ cross,
    const int* __restrict__ position,
    float* __restrict__ Ssum) {
    const int tile = blockIdx.x;          // 0..NT2-1
    const int p = blockIdx.y;
    const int n0g = tile * TNB;
    const int t = threadIdx.x;
    const int l = t & 63;                 // lane
    const int w = t >> 6;                 // wave 0..3
    const int m0w = (w & 1) * 64;         // wave m-offset (b)
    const int n0w = (w >> 1) * 64;        // wave n-offset

    __shared__ unsigned short As[2][128 * KP2];   // feature tile, bf16, dbuf
    __shared__ unsigned short Bs[2][128 * KP2];   // centers tile, bf16, dbuf
    __shared__ float cn2s[128];
    __shared__ float fn2s[128];
    __shared__ float red[128];
    __shared__ float msk[128];

    if (t < 128) { red[t] = 0.0f; msk[t] = 1.0f; }

    f32x4 acc[4][4];
    #pragma unroll
    for (int i = 0; i < 4; ++i)
        #pragma unroll
        for (int j = 0; j < 4; ++j) acc[i][j] = (f32x4)0.0f;

    float c2acc[4] = {0.0f, 0.0f, 0.0f, 0.0f};    // centers row sumsq partials
    float a2acc[4] = {0.0f, 0.0f, 0.0f, 0.0f};    // feature row sumsq partials

    const float* Ab = feature + (size_t)p * B_ * D_;
    const float* Bb = centers + ((size_t)p * N_ + n0g) * D_;

    const int f8 = t & 7;                 // which float4 within a 32-float row chunk
    const int r0 = t >> 3;                // 0..31; rows r0 + 32*i

    float4 va0[4], vb0[4], va1[4], vb1[4];

#define LOAD_SET(va, vb, kk) \
    _Pragma("unroll") \
    for (int i = 0; i < 4; ++i) { \
        const int row = r0 + 32 * i; \
        va[i] = *(const float4*)(Ab + (size_t)row * D_ + (kk) + f8 * 4); \
        vb[i] = *(const float4*)(Bb + (size_t)row * D_ + (kk) + f8 * 4); \
    }

#define PACK_SET(va, vb, buf) \
    _Pragma("unroll") \
    for (int i = 0; i < 4; ++i) { \
        const int row = r0 + 32 * i; \
        *(uint2*)&As[buf][row * KP2 + f8 * 4] = pack_bf16x4(va[i]); \
        *(uint2*)&Bs[buf][row * KP2 + f8 * 4] = pack_bf16x4(vb[i]); \
        a2acc[i] += va[i].x * va[i].x + va[i].y * va[i].y \
                  + va[i].z * va[i].z + va[i].w * va[i].w; \
        c2acc[i] += vb[i].x * vb[i].x + vb[i].y * vb[i].y \
                  + vb[i].z * vb[i].z + vb[i].w * vb[i].w; \
    }

    // prologue: issue chunk0 -> set0, chunk1 -> set1; stage chunk0 into buf0
    LOAD_SET(va0, vb0, 0)
    LOAD_SET(va1, vb1, BK2)
    PACK_SET(va0, vb0, 0)
    LDS_BARRIER();

    // column mask for this tile (init ordered before scatter by the barrier;
    // scatter ordered before epilogue read by the chunk-loop barriers)
    for (int i = t; i < B_ * K_ + B_; i += 256) {
        const int v = (i < B_ * K_) ? cross[i] : position[i - B_ * K_];
        const unsigned rr = (unsigned)(v - n0g);
        if (rr < (unsigned)TNB) msk[rr] = 0.0f;
    }

    const int ko = (l >> 4) * 8;          // frag k-offset in shorts
    const int fr = l & 15;
    #pragma unroll
    for (int c = 0; c < NCH; ++c) {
        const int cur = c & 1;
        // 1. issue loads for chunk c+2 into the set freed last iteration
        if (c + 2 < NCH) {
            if (cur == 0) { LOAD_SET(va0, vb0, (c + 2) * BK2) }
            else          { LOAD_SET(va1, vb1, (c + 2) * BK2) }
        }
        // 2. fragments from buf[cur] + MFMA
        bf16x8 af[4], bfr[4];
        #pragma unroll
        for (int i = 0; i < 4; ++i) {
            af[i]  = *(const bf16x8*)&As[cur][(m0w + i * 16 + fr) * KP2 + ko];
            bfr[i] = *(const bf16x8*)&Bs[cur][(n0w + i * 16 + fr) * KP2 + ko];
        }
        #pragma unroll
        for (int i = 0; i < 4; ++i)
            #pragma unroll
            for (int j = 0; j < 4; ++j)
                acc[i][j] = __builtin_amdgcn_mfma_f32_16x16x32_bf16(
                    af[i], bfr[j], acc[i][j], 0, 0, 0);
        // 3. pack chunk c+1 (waits exactly its own loads via counted vmcnt)
        if (c + 1 < NCH) {
            if (cur == 0) { PACK_SET(va1, vb1, 1) }
            else          { PACK_SET(va0, vb0, 0) }
        }
        LDS_BARRIER();
    }

#undef LOAD_SET
#undef PACK_SET

    // cn2/fn2: reduce lane-local partials across the 8 f8 lanes of each row
    #pragma unroll
    for (int i = 0; i < 4; ++i) {
        float s = c2acc[i];
        s += __shfl_xor(s, 1); s += __shfl_xor(s, 2); s += __shfl_xor(s, 4);
        float sa = a2acc[i];
        sa += __shfl_xor(sa, 1); sa += __shfl_xor(sa, 2); sa += __shfl_xor(sa, 4);
        if (f8 == 0) { cn2s[r0 + 32 * i] = s; fn2s[r0 + 32 * i] = sa; }
    }
    LDS_BARRIER();

    // epilogue: C/D layout col=lane&15 (n), row=(lane>>4)*4+reg (b)  [m89/m91]
    float c2l[4], mkl[4];
    #pragma unroll
    for (int j = 0; j < 4; ++j) {
        const int col = n0w + j * 16 + fr;
        c2l[j] = cn2s[col];
        mkl[j] = msk[col];
    }
    #pragma unroll
    for (int i = 0; i < 4; ++i) {
        #pragma unroll
        for (int r = 0; r < 4; ++r) {
            const int row = m0w + i * 16 + (l >> 4) * 4 + r;
            const float fv = fn2s[row];
            float s = 0.0f;
            #pragma unroll
            for (int j = 0; j < 4; ++j) {
                const float nd2 = fv + c2l[j] - 2.0f * acc[i][j][r];
                s += mkl[j] * __expf(-10.0f * sqrtf(fmaxf(nd2, 1e-12f)));
            }
            s += __shfl_xor(s, 1); s += __shfl_xor(s, 2);
            s += __shfl_xor(s, 4); s += __shfl_xor(s, 8);
            if (fr == 0) atomicAdd(&red[row], s);   // LDS atomic, 2 adds/row
        }
    }
    LDS_BARRIER();
    if (t < 128) atomicAdd(&Ssum[p * B_ + t], red[t]);   // device-scope f32 add
}

// ---------- final scalars + pos_vid gather (diff computed inline from Ssum) ----------
__global__ void final_kernel(const float* __restrict__ validf,
                             const float* __restrict__ klrow,
                             const float* __restrict__ xarr,
                             const float* __restrict__ Ssum,
                             const int* __restrict__ cross,
                             const int* __restrict__ vid,
                             float* __restrict__ out) {
    const int t = threadIdx.x;            // 128
    __shared__ float sh[128];
    __shared__ float accum[2];            // [0]=contrastive sum over p, [1]=align
    if (t == 0) { accum[0] = 0.0f; accum[1] = 0.0f; }
    __syncthreads();
    for (int p = 0; p < P_; ++p) {
        float nv = block_sum_128(validf[p * B_ + t], sh);
        float ks = block_sum_128(klrow[p * B_ + t], sh);
        float dv = logf(Ssum[p * B_ + t]) - xarr[p * B_ + t];
        float ds = block_sum_128(dv, sh);
        if (t == 0) {
            float lp = ds / (float)B_;
            if (!(lp != lp)) accum[0] += lp;                    // where(isnan, 0)
            if (nv > 0.5f) accum[1] += 0.5f * ks / fmaxf(nv, 1.0f);
        }
        __syncthreads();
    }
    if (t == 0) {
        float contrastive = accum[0] / (float)P_;
        float align = accum[1];
        out[1] = contrastive;
        out[2] = align;
        // KL_WEIGHT = max(0.5*(1 - 1/60), 0.1)
        out[0] = contrastive + 0.49166666666666664f * align;
    }
    #pragma unroll
    for (int k = 0; k < K_; ++k) {
        const int i = k * 128 + t;        // 0..1279
        out[3 + i] = (float)vid[cross[i]];
    }
}

extern "C" void kernel_launch(void* const* d_in, const int* in_sizes, int n_in,
                              void* d_out, int out_size, void* d_ws, size_t ws_size,
                              hipStream_t stream) {
    const float* feature      = (const float*)d_in[0];
    const float* text_feature = (const float*)d_in[1];
    const float* centers      = (const float*)d_in[2];
    const int*   position     = (const int*)d_in[3];
    const int*   cross        = (const int*)d_in[4];
    const int*   vid          = (const int*)d_in[5];
    float* out = (float*)d_out;

    // workspace layout (floats)
    float* ws      = (float*)d_ws;
    float* img_sim = ws;                                  // P*B*B
    float* txt_sim = img_sim + (size_t)P_ * B_ * B_;      // P*B*B
    float* validf  = txt_sim + (size_t)P_ * B_ * B_;      // P*B
    float* klrow   = validf + P_ * B_;                    // P*B
    float* xarr    = klrow + P_ * B_;                     // P*B
    float* Ssum    = xarr + P_ * B_;                      // P*B

    sim_kernel<<<dim3(P_, B_ / 2), 128, 0, stream>>>(feature, text_feature,
                                                     img_sim, txt_sim, validf, Ssum);
    kl_kernel<<<dim3(P_, B_ / 4), 256, 0, stream>>>(img_sim, txt_sim, validf, klrow);
    posx_kernel<<<P_ * B_, 64, 0, stream>>>(feature, centers, cross, xarr);
    neg_mfma_kernel<<<dim3(NT2, P_), 256, 0, stream>>>(feature, centers, cross,
                                                       position, Ssum);
    final_kernel<<<1, 128, 0, stream>>>(validf, klrow, xarr, Ssum, cross, vid, out);
}

// Round 2
// 452.894 us; speedup vs baseline: 1.2909x; 1.2909x over previous
//
#include <hip/hip_runtime.h>
#include <hip/hip_bf16.h>
#include <math.h>

// Problem constants (from reference setup_inputs)
#define P_ 4
#define B_ 128
#define D_ 512
#define N_ 32768
#define K_ 10
#define TNB 128          // n-tile per block in neg_mfma_kernel
#define NT2 (N_ / TNB)   // 256 tiles per p
#define BK2 32           // k-chunk (1 MFMA K-step)
#define NCH (D_ / BK2)   // 16 chunks
#define KP2 42           // padded LDS row stride in shorts (32 + 10): 21-dword rows,
                         // odd stride coprime with 32 banks -> near-conflict-free b128

typedef __attribute__((ext_vector_type(8))) short bf16x8;   // 8 bf16 (4 VGPRs)
typedef __attribute__((ext_vector_type(4))) float f32x4;    // MFMA acc

// Workgroup barrier that does NOT drain vmcnt: own LDS ops must be complete
// (lgkmcnt(0)) for cross-thread visibility, but register-destined global
// loads (the next chunk's A fragments) stay in flight across the barrier.
#define LDS_BARRIER() asm volatile("s_waitcnt lgkmcnt(0)\n\ts_barrier" ::: "memory")

static __device__ __forceinline__ float block_sum_128(float v, float* sh) {
    const int t = threadIdx.x;
    sh[t] = v; __syncthreads();
    #pragma unroll
    for (int s = 64; s > 0; s >>= 1) { if (t < s) sh[t] += sh[t + s]; __syncthreads(); }
    float r = sh[0]; __syncthreads();
    return r;
}

static __device__ __forceinline__ uint2 pack_bf16x4(float4 v) {
    union { __hip_bfloat162 h; unsigned u; } lo, hi;
    lo.h = __float22bfloat162_rn(make_float2(v.x, v.y));   // RNE
    hi.h = __float22bfloat162_rn(make_float2(v.z, v.w));
    uint2 r; r.x = lo.u; r.y = hi.u;
    return r;
}

// ---------- prep: feature -> bf16 copy (for direct A-frag loads) + fn2 ----------
__global__ __launch_bounds__(256) void prep_kernel(const float* __restrict__ feature,
                                                   unsigned short* __restrict__ Abf,
                                                   float* __restrict__ fn2) {
    const int pb = blockIdx.x;            // 0..P*B-1
    const int t = threadIdx.x;            // 256 threads, 2 consecutive elems each
    const float2 v = *(const float2*)(feature + (size_t)pb * D_ + 2 * t);
    union { __hip_bfloat162 h; unsigned u; } pk;
    pk.h = __float22bfloat162_rn(make_float2(v.x, v.y));
    ((unsigned*)Abf)[(size_t)pb * (D_ / 2) + t] = pk.u;
    __shared__ float sred[256];
    sred[t] = v.x * v.x + v.y * v.y;
    __syncthreads();
    #pragma unroll
    for (int s = 128; s > 0; s >>= 1) { if (t < s) sred[t] += sred[t + s]; __syncthreads(); }
    if (t == 0) fn2[pb] = sred[0];
}

// ---------- sim: fused normalize + similarity + valid; also zeroes Ssum ----------
__global__ __launch_bounds__(128) void sim_kernel(
    const float* __restrict__ feature,
    const float* __restrict__ text_feature,
    float* __restrict__ img_sim,
    float* __restrict__ txt_sim,
    float* __restrict__ validf,
    float* __restrict__ Ssum) {
    const int p = blockIdx.x;
    const int b0 = blockIdx.y * 2;        // 2 rows per block
    const int c = threadIdx.x;            // 128 threads, one column each
    if (blockIdx.y == 0) Ssum[p * B_ + c] = 0.0f;   // zero accumulator for neg_mfma
    __shared__ float ai[2][D_];
    __shared__ float at[2][D_];
    __shared__ float cinv_i[128];
    __shared__ float cinv_t[128];
    __shared__ int flags[2];
    #pragma unroll
    for (int i = 0; i < 8; ++i) {
        int idx = c + i * 128;            // 0..1023
        int row = idx >> 9, d = idx & 511;
        ai[row][d] = feature[(size_t)(p * B_ + b0 + row) * D_ + d];
        at[row][d] = text_feature[((size_t)(b0 + row) * P_ + p) * D_ + d];
    }
    if (c < 2) flags[c] = 0;
    __syncthreads();
    float di[2] = {0, 0};
    float dt[2] = {0, 0};
    float ssi = 0.0f, sst = 0.0f;         // column sumsq (raw)
    const float* fc = feature + (size_t)(p * B_ + c) * D_;
    const float* tc = text_feature + ((size_t)c * P_ + p) * D_;
    for (int d = 0; d < D_; d += 4) {
        float4 vi = *(const float4*)(fc + d);
        float4 vt = *(const float4*)(tc + d);
        ssi += vi.x * vi.x + vi.y * vi.y + vi.z * vi.z + vi.w * vi.w;
        sst += vt.x * vt.x + vt.y * vt.y + vt.z * vt.z + vt.w * vt.w;
        #pragma unroll
        for (int i = 0; i < 2; ++i) {
            float4 a4 = *(const float4*)&ai[i][d];
            float4 t4 = *(const float4*)&at[i][d];
            di[i] += a4.x * vi.x + a4.y * vi.y + a4.z * vi.z + a4.w * vi.w;
            dt[i] += t4.x * vt.x + t4.y * vt.y + t4.z * vt.z + t4.w * vt.w;
        }
    }
    cinv_i[c] = 1.0f / fmaxf(sqrtf(ssi), 1e-12f);
    cinv_t[c] = 1.0f / fmaxf(sqrtf(sst), 1e-12f);
    __syncthreads();
    #pragma unroll
    for (int i = 0; i < 2; ++i) {
        float is = 2.0f * di[i] * cinv_i[b0 + i] * cinv_i[c];   // / TEMP (0.5)
        float ts = 2.0f * dt[i] * cinv_t[b0 + i] * cinv_t[c];
        img_sim[(size_t)(p * B_ + b0 + i) * B_ + c] = is;
        txt_sim[(size_t)(p * B_ + b0 + i) * B_ + c] = ts;
        if (is > 0.7f && ts > 0.7f) flags[i] = 1;   // benign write race
    }
    __syncthreads();
    if (c < 2) validf[p * B_ + b0 + c] = (float)flags[c];
}

// ---------- per-row masked log-softmax + symmetric KL (one wave per row) ----------
__global__ __launch_bounds__(256) void kl_kernel(
    const float* __restrict__ img_sim,
    const float* __restrict__ txt_sim,
    const float* __restrict__ validf,
    float* __restrict__ klrow) {
    const int l = threadIdx.x & 63;
    const int wv = threadIdx.x >> 6;
    const int p = blockIdx.x;
    const int r = blockIdx.y * 4 + wv;
    const size_t base = (size_t)(p * B_ + r) * B_;
    const bool v0 = validf[p * B_ + l] > 0.5f;
    const bool v1 = validf[p * B_ + 64 + l] > 0.5f;
    const float il0 = v0 ? img_sim[base + l] : -1e30f;
    const float il1 = v1 ? img_sim[base + 64 + l] : -1e30f;
    const float tl0 = v0 ? txt_sim[base + l] : -1e30f;
    const float tl1 = v1 ? txt_sim[base + 64 + l] : -1e30f;
    float mi = fmaxf(il0, il1), mt = fmaxf(tl0, tl1);
    #pragma unroll
    for (int off = 32; off > 0; off >>= 1) {
        mi = fmaxf(mi, __shfl_xor(mi, off));
        mt = fmaxf(mt, __shfl_xor(mt, off));
    }
    float si = expf(il0 - mi) + expf(il1 - mi);
    float st = expf(tl0 - mt) + expf(tl1 - mt);
    #pragma unroll
    for (int off = 32; off > 0; off >>= 1) {
        si += __shfl_xor(si, off);
        st += __shfl_xor(st, off);
    }
    const float lsei = mi + logf(si);
    const float lset = mt + logf(st);
    float term = 0.0f;
    if (v0) {
        float lpi = il0 - lsei, lpt = tl0 - lset;
        term += expf(lpt) * (lpt - lpi) + expf(lpi) * (lpi - lpt);
    }
    if (v1) {
        float lpi = il1 - lsei, lpt = tl1 - lset;
        term += expf(lpt) * (lpt - lpi) + expf(lpi) * (lpi - lpt);
    }
    #pragma unroll
    for (int off = 32; off > 0; off >>= 1) term += __shfl_xor(term, off);
    if (l == 0) klrow[p * B_ + r] = (validf[p * B_ + r] > 0.5f) ? term : 0.0f;
}

// ---------- x[p,b] = log sum_k exp(-SCALE * pos_dist); fn2 computed inline ----------
__global__ void posx_kernel(const float* __restrict__ feature,
                            const float* __restrict__ centers,
                            const int* __restrict__ cross,
                            float* __restrict__ xarr) {
    const int pb = blockIdx.x;
    const int p = pb >> 7, b = pb & 127;
    const int l = threadIdx.x;            // 64 (one wave)
    const float* f = feature + (size_t)pb * D_;
    float4 f0 = *(const float4*)(f + l * 4);
    float4 f1 = *(const float4*)(f + 256 + l * 4);
    float fs = f0.x * f0.x + f0.y * f0.y + f0.z * f0.z + f0.w * f0.w
             + f1.x * f1.x + f1.y * f1.y + f1.z * f1.z + f1.w * f1.w;
    #pragma unroll
    for (int off = 32; off > 0; off >>= 1) fs += __shfl_down(fs, off);
    // fs = ||f||^2 valid on lane 0
    float ex = 0.0f;
    #pragma unroll
    for (int k = 0; k < K_; ++k) {
        int idx = cross[b * K_ + k];
        const float* cp = centers + ((size_t)p * N_ + idx) * D_;
        float4 c0 = *(const float4*)(cp + l * 4);
        float4 c1 = *(const float4*)(cp + 256 + l * 4);
        float dot = f0.x * c0.x + f0.y * c0.y + f0.z * c0.z + f0.w * c0.w
                  + f1.x * c1.x + f1.y * c1.y + f1.z * c1.z + f1.w * c1.w;
        float pn2 = c0.x * c0.x + c0.y * c0.y + c0.z * c0.z + c0.w * c0.w
                  + c1.x * c1.x + c1.y * c1.y + c1.z * c1.z + c1.w * c1.w;
        #pragma unroll
        for (int off = 32; off > 0; off >>= 1) {
            dot += __shfl_down(dot, off);
            pn2 += __shfl_down(pn2, off);
        }
        if (l == 0) {
            float d2 = fs + pn2 - 2.0f * dot;
            ex += expf(-10.0f * sqrtf(fmaxf(d2, 1e-12f)));
        }
    }
    if (l == 0) xarr[pb] = logf(ex);
}

// ---------- main kernel: bf16 MFMA GEMM + fused sqrt/exp/mask epilogue ----------
// v3: A fragments loaded DIRECTLY from global bf16 (L2-resident, 64B-segment
// coalesced) -> no As LDS, no A pack, half the staging registers. B staged
// f32->bf16 in LDS with 1-deep prefetch. Non-draining barriers keep the next
// chunk's A-frag loads in flight. unroll 2 only (full unroll caused spills).
__global__ __launch_bounds__(256) void neg_mfma_kernel(
    const unsigned short* __restrict__ Abf,
    const float* __restrict__ centers,
    const float* __restrict__ fn2,
    const int* __restrict__ cross,
    const int* __restrict__ position,
    float* __restrict__ Ssum) {
    const int tile = blockIdx.x;          // 0..NT2-1
    const int p = blockIdx.y;
    const int n0g = tile * TNB;
    const int t = threadIdx.x;
    const int l = t & 63;                 // lane
    const int w = t >> 6;                 // wave 0..3
    const int m0w = (w & 1) * 64;         // wave m-offset (b)
    const int n0w = (w >> 1) * 64;        // wave n-offset

    __shared__ unsigned short Bs[2][128 * KP2];   // centers tile, bf16, dbuf
    __shared__ float cn2s[128];
    __shared__ float fn2s[128];
    __shared__ float red[128];
    __shared__ float msk[128];

    if (t < 128) { red[t] = 0.0f; msk[t] = 1.0f; fn2s[t] = fn2[p * B_ + t]; }

    f32x4 acc[4][4];
    #pragma unroll
    for (int i = 0; i < 4; ++i)
        #pragma unroll
        for (int j = 0; j < 4; ++j) acc[i][j] = (f32x4)0.0f;

    float c2acc[4] = {0.0f, 0.0f, 0.0f, 0.0f};    // centers row sumsq partials

    const float* Bb = centers + ((size_t)p * N_ + n0g) * D_;

    const int f8 = t & 7;                 // which float4 within a 32-float row chunk
    const int r0 = t >> 3;                // 0..31; rows r0 + 32*i

    const int ko = (l >> 4) * 8;          // frag k-offset in elems
    const int fr = l & 15;
    // per-lane A-frag base: row m0w+fr (+i*16 rows), k-offset ko (+c*32)
    const unsigned short* Afr = Abf + ((size_t)p * B_ + m0w + fr) * D_ + ko;

    float4 vb[4];
    bf16x8 afc[4], afn[4];

    // prologue: B chunk0 -> regs -> pack buf0; A chunk0 frags -> regs
    #pragma unroll
    for (int i = 0; i < 4; ++i)
        vb[i] = *(const float4*)(Bb + (size_t)(r0 + 32 * i) * D_ + f8 * 4);
    #pragma unroll
    for (int i = 0; i < 4; ++i)
        afc[i] = *(const bf16x8*)(Afr + (size_t)(i * 16) * D_);
    #pragma unroll
    for (int i = 0; i < 4; ++i) {
        const int row = r0 + 32 * i;
        *(uint2*)&Bs[0][row * KP2 + f8 * 4] = pack_bf16x4(vb[i]);
        c2acc[i] += vb[i].x * vb[i].x + vb[i].y * vb[i].y
                  + vb[i].z * vb[i].z + vb[i].w * vb[i].w;
    }
    LDS_BARRIER();

    // column mask for this tile (init ordered before scatter by the barrier;
    // scatter ordered before epilogue read by the chunk-loop barriers)
    for (int i = t; i < B_ * K_ + B_; i += 256) {
        const int v = (i < B_ * K_) ? cross[i] : position[i - B_ * K_];
        const unsigned rr = (unsigned)(v - n0g);
        if (rr < (unsigned)TNB) msk[rr] = 0.0f;
    }

    #pragma unroll 2
    for (int c = 0; c < NCH; ++c) {
        const int cur = c & 1;
        // 1. issue next chunk's loads (B f32 -> regs, A bf16 frags -> regs)
        if (c + 1 < NCH) {
            const int kk = (c + 1) * BK2;
            #pragma unroll
            for (int i = 0; i < 4; ++i)
                vb[i] = *(const float4*)(Bb + (size_t)(r0 + 32 * i) * D_ + kk + f8 * 4);
            #pragma unroll
            for (int i = 0; i < 4; ++i)
                afn[i] = *(const bf16x8*)(Afr + (size_t)(i * 16) * D_ + kk);
        }
        // 2. B fragments from Bs[cur] + MFMA
        bf16x8 bfr[4];
        #pragma unroll
        for (int i = 0; i < 4; ++i)
            bfr[i] = *(const bf16x8*)&Bs[cur][(n0w + i * 16 + fr) * KP2 + ko];
        #pragma unroll
        for (int i = 0; i < 4; ++i)
            #pragma unroll
            for (int j = 0; j < 4; ++j)
                acc[i][j] = __builtin_amdgcn_mfma_f32_16x16x32_bf16(
                    afc[i], bfr[j], acc[i][j], 0, 0, 0);
        // 3. pack next B chunk (waits exactly its own loads via counted vmcnt)
        if (c + 1 < NCH) {
            #pragma unroll
            for (int i = 0; i < 4; ++i) {
                const int row = r0 + 32 * i;
                *(uint2*)&Bs[cur ^ 1][row * KP2 + f8 * 4] = pack_bf16x4(vb[i]);
                c2acc[i] += vb[i].x * vb[i].x + vb[i].y * vb[i].y
                          + vb[i].z * vb[i].z + vb[i].w * vb[i].w;
            }
        }
        LDS_BARRIER();            // afn (registers) stays in flight across this
        #pragma unroll
        for (int i = 0; i < 4; ++i) afc[i] = afn[i];
    }

    // cn2: reduce lane-local partials across the 8 f8 lanes of each row
    #pragma unroll
    for (int i = 0; i < 4; ++i) {
        float s = c2acc[i];
        s += __shfl_xor(s, 1); s += __shfl_xor(s, 2); s += __shfl_xor(s, 4);
        if (f8 == 0) cn2s[r0 + 32 * i] = s;
    }
    LDS_BARRIER();

    // epilogue: C/D layout col=lane&15 (n), row=(lane>>4)*4+reg (b)  [m89/m91]
    float c2l[4], mkl[4];
    #pragma unroll
    for (int j = 0; j < 4; ++j) {
        const int col = n0w + j * 16 + fr;
        c2l[j] = cn2s[col];
        mkl[j] = msk[col];
    }
    #pragma unroll
    for (int i = 0; i < 4; ++i) {
        #pragma unroll
        for (int r = 0; r < 4; ++r) {
            const int row = m0w + i * 16 + (l >> 4) * 4 + r;
            const float fv = fn2s[row];
            float s = 0.0f;
            #pragma unroll
            for (int j = 0; j < 4; ++j) {
                const float nd2 = fv + c2l[j] - 2.0f * acc[i][j][r];
                s += mkl[j] * __expf(-10.0f * sqrtf(fmaxf(nd2, 1e-12f)));
            }
            s += __shfl_xor(s, 1); s += __shfl_xor(s, 2);
            s += __shfl_xor(s, 4); s += __shfl_xor(s, 8);
            if (fr == 0) atomicAdd(&red[row], s);   // LDS atomic, 2 adds/row
        }
    }
    LDS_BARRIER();
    if (t < 128) atomicAdd(&Ssum[p * B_ + t], red[t]);   // device-scope f32 add
}

// ---------- final scalars + pos_vid gather (diff computed inline from Ssum) ----------
__global__ void final_kernel(const float* __restrict__ validf,
                             const float* __restrict__ klrow,
                             const float* __restrict__ xarr,
                             const float* __restrict__ Ssum,
                             const int* __restrict__ cross,
                             const int* __restrict__ vid,
                             float* __restrict__ out) {
    const int t = threadIdx.x;            // 128
    __shared__ float sh[128];
    __shared__ float accum[2];            // [0]=contrastive sum over p, [1]=align
    if (t == 0) { accum[0] = 0.0f; accum[1] = 0.0f; }
    __syncthreads();
    for (int p = 0; p < P_; ++p) {
        float nv = block_sum_128(validf[p * B_ + t], sh);
        float ks = block_sum_128(klrow[p * B_ + t], sh);
        float dv = logf(Ssum[p * B_ + t]) - xarr[p * B_ + t];
        float ds = block_sum_128(dv, sh);
        if (t == 0) {
            float lp = ds / (float)B_;
            if (!(lp != lp)) accum[0] += lp;                    // where(isnan, 0)
            if (nv > 0.5f) accum[1] += 0.5f * ks / fmaxf(nv, 1.0f);
        }
        __syncthreads();
    }
    if (t == 0) {
        float contrastive = accum[0] / (float)P_;
        float align = accum[1];
        out[1] = contrastive;
        out[2] = align;
        // KL_WEIGHT = max(0.5*(1 - 1/60), 0.1)
        out[0] = contrastive + 0.49166666666666664f * align;
    }
    #pragma unroll
    for (int k = 0; k < K_; ++k) {
        const int i = k * 128 + t;        // 0..1279
        out[3 + i] = (float)vid[cross[i]];
    }
}

extern "C" void kernel_launch(void* const* d_in, const int* in_sizes, int n_in,
                              void* d_out, int out_size, void* d_ws, size_t ws_size,
                              hipStream_t stream) {
    const float* feature      = (const float*)d_in[0];
    const float* text_feature = (const float*)d_in[1];
    const float* centers      = (const float*)d_in[2];
    const int*   position     = (const int*)d_in[3];
    const int*   cross        = (const int*)d_in[4];
    const int*   vid          = (const int*)d_in[5];
    float* out = (float*)d_out;

    // workspace layout (floats)
    float* ws      = (float*)d_ws;
    float* img_sim = ws;                                  // P*B*B
    float* txt_sim = img_sim + (size_t)P_ * B_ * B_;      // P*B*B
    float* validf  = txt_sim + (size_t)P_ * B_ * B_;      // P*B
    float* klrow   = validf + P_ * B_;                    // P*B
    float* xarr    = klrow + P_ * B_;                     // P*B
    float* Ssum    = xarr + P_ * B_;                      // P*B
    float* fn2     = Ssum + P_ * B_;                      // P*B
    unsigned short* Abf = (unsigned short*)(fn2 + P_ * B_);  // P*B*D bf16

    prep_kernel<<<P_ * B_, 256, 0, stream>>>(feature, Abf, fn2);
    sim_kernel<<<dim3(P_, B_ / 2), 128, 0, stream>>>(feature, text_feature,
                                                     img_sim, txt_sim, validf, Ssum);
    kl_kernel<<<dim3(P_, B_ / 4), 256, 0, stream>>>(img_sim, txt_sim, validf, klrow);
    posx_kernel<<<P_ * B_, 64, 0, stream>>>(feature, centers, cross, xarr);
    neg_mfma_kernel<<<dim3(NT2, P_), 256, 0, stream>>>(Abf, centers, fn2, cross,
                                                       position, Ssum);
    final_kernel<<<1, 128, 0, stream>>>(validf, klrow, xarr, Ssum, cross, vid, out);
}